// Round 1
// baseline (103.777 us; speedup 1.0000x reference)
//
#include <hip/hip_runtime.h>

// Problem constants (reference: N=32768, M=8192, D=64, fp32)
#define N_ROWS 32768
#define M_COLS 8192
#define D_DIM  64
#define JC     8                      // j-chunks (grid.y)
#define PBLOCK 256                    // prep block size
#define BLOCK  256                    // partial_min: 4 waves/block
#define RBLOCK 128                    // reduce block size (256 blocks -> all CUs)
#define GROUPS 2                      // 32-col i-groups per wave -> 64 i/wave
#define ROWS_PER_BLOCK 256            // 4 waves x 64 i; grid.x=128 -> 4 blocks/CU
#define CHUNK  (M_COLS / JC)          // 1024 j per chunk
#define TJ     128                    // j per LDS tile (128 rows x 128 B = 16 KB)
#define NTILE  (CHUNK / TJ)           // 8 tiles per chunk

typedef _Float16 v8h  __attribute__((ext_vector_type(8)));
typedef _Float16 v4h  __attribute__((ext_vector_type(4)));
typedef float    v4f  __attribute__((ext_vector_type(4)));
typedef float    v16f __attribute__((ext_vector_type(16)));

// ---------- kernel 1: yh=(half)y, th[j]=(psi-||y||^2)/2, xh=(half)x, x2[i]=||x||^2 ----------
// blocks [0, M/16): y rows (+ th); blocks [M/16, M/16+N/16): x rows (+ x2).
__global__ __launch_bounds__(PBLOCK) void prep_kernel(
    const float* __restrict__ y, const float* __restrict__ psi,
    const float* __restrict__ x, _Float16* __restrict__ yh,
    float* __restrict__ th, _Float16* __restrict__ xh,
    float* __restrict__ x2, float* __restrict__ out) {
    const int tid = threadIdx.x;
    const int bid = blockIdx.x;
    const int n = tid & 15;                      // 4-elem segment
    if (bid < M_COLS / 16) {
        if (bid == 0 && tid == 0) out[0] = 0.f;  // atomic accumulator init
        const int j = bid * 16 + (tid >> 4);     // y row
        const float4 v = *(const float4*)(y + (size_t)j * D_DIM + n * 4);
        float s = v.x * v.x + v.y * v.y + v.z * v.z + v.w * v.w;
        v4h hv = { (_Float16)v.x, (_Float16)v.y, (_Float16)v.z, (_Float16)v.w };
        *(v4h*)(yh + (size_t)j * D_DIM + n * 4) = hv;
#pragma unroll
        for (int m = 1; m < 16; m <<= 1) s += __shfl_xor(s, m, 64);
        if (n == 0) th[j] = 0.5f * (psi[j] - s);   // plain scalar (32x32 C-init reads rows)
    } else {
        const int i = (bid - M_COLS / 16) * 16 + (tid >> 4);  // x row
        const float4 v = *(const float4*)(x + (size_t)i * D_DIM + n * 4);
        float s = v.x * v.x + v.y * v.y + v.z * v.z + v.w * v.w;
        v4h hv = { (_Float16)v.x, (_Float16)v.y, (_Float16)v.z, (_Float16)v.w };
        *(v4h*)(xh + (size_t)i * D_DIM + n * 4) = hv;
#pragma unroll
        for (int m = 1; m < 16; m <<= 1) s += __shfl_xor(s, m, 64);
        if (n == 0) x2[i] = s;                     // reduce no longer re-reads 8 MB of x
    }
}

// ---------- kernel 2: MFMA partial min over a j-chunk (32x32x16, A=y B=x) ----------
// part[jc*N + i] = min_{j in chunk} (t[j] - 2<x_i,y_j>) = -2 max_j(<x_i,y_j>+th[j])
// Swapped operands: A = y-tile rows (j), B = x fragments (i cols). C-row = j, so the
// th[j] C-init comes straight from 4 broadcast ds_read_b128 and the j-max is a pure
// per-lane register max (maxs = 2 scalars; epilogue = one shfl_xor(32) + coalesced store).
__global__ __launch_bounds__(BLOCK, 4) void partial_min_kernel(
    const _Float16* __restrict__ xh, const _Float16* __restrict__ yh,
    const float* __restrict__ th, float* __restrict__ part) {
    __shared__ __align__(16) _Float16 sY[2][TJ * D_DIM];  // 2 x 16 KB
    __shared__ __align__(16) float    sTh[2][TJ];         // 2 x 512 B

    const int tid  = threadIdx.x;
    const int lane = tid & 63, wave = tid >> 6;
    const int hi = lane >> 5, r32 = lane & 31;
    const int jc    = blockIdx.y;
    const int jbase = jc * CHUNK;
    const int i_wave = blockIdx.x * ROWS_PER_BLOCK + wave * 64;

    // ---- async stage of tile t into buffer b (XOR-swizzled on the GLOBAL side) ----
    // LDS 16B-slot sIdx holds (row = sIdx/8, chunk = (sIdx%8) ^ (row&7)).
    auto stage = [&](int t, int b) {
#pragma unroll
        for (int k = 0; k < 4; ++k) {
            const int sIdx = (k * 4 + wave) * 64 + lane;     // [0,1024)
            const int row  = sIdx >> 3;
            const int c    = (sIdx & 7) ^ (row & 7);
            const _Float16* g = yh + (size_t)(jbase + t * TJ + row) * D_DIM + c * 8;
            __builtin_amdgcn_global_load_lds(
                (const __attribute__((address_space(1))) void*)g,
                (__attribute__((address_space(3))) void*)(&sY[b][(size_t)(k * 4 + wave) * 512]),
                16, 0, 0);
        }
        // th tile: TJ*4 B = 512 B via wave 0 lanes 0..31 (16 B each, linear)
        if (wave == 0 && lane < 32) {
            const float* gt_ = th + (size_t)(jbase + t * TJ) + lane * 4;
            __builtin_amdgcn_global_load_lds(
                (const __attribute__((address_space(1))) void*)gt_,
                (__attribute__((address_space(3))) void*)(&sTh[b][0]),
                16, 0, 0);
        }
    };

    stage(0, 0);  // start tile-0 DMA first; overlaps the B-frag loads below

    // x B-frags: 2 col-groups x 4 k-slices; lane holds col=r32, k=ks*16+hi*8+e
    v8h b[GROUPS][4];
#pragma unroll
    for (int g = 0; g < GROUPS; ++g) {
        const _Float16* px = xh + (size_t)(i_wave + g * 32 + r32) * D_DIM + hi * 8;
#pragma unroll
        for (int ks = 0; ks < 4; ++ks) b[g][ks] = *(const v8h*)(px + ks * 16);
    }

    float maxs[GROUPS];
#pragma unroll
    for (int g = 0; g < GROUPS; ++g) maxs[g] = -INFINITY;

    // per-lane swizzled byte offsets for the 4 k-chunk A reads (row&7 == r32&7)
    int aoff0 = r32 * 128 + (((0 * 2 + hi) ^ (r32 & 7)) * 16);
    int aoff1 = r32 * 128 + (((1 * 2 + hi) ^ (r32 & 7)) * 16);
    int aoff2 = r32 * 128 + (((2 * 2 + hi) ^ (r32 & 7)) * 16);
    int aoff3 = r32 * 128 + (((3 * 2 + hi) ^ (r32 & 7)) * 16);

    __syncthreads();  // drains vmcnt(0): tile 0 + B-frags resident

    for (int t = 0; t < NTILE; ++t) {
        const int cur = t & 1;
        if (t + 1 < NTILE) stage(t + 1, cur ^ 1);  // prefetch under compute

        const char*  buf  = (const char*)&sY[cur][0];
        const float* tbuf = &sTh[cur][0];
#pragma unroll
        for (int jb = 0; jb < TJ / 32; ++jb) {
            // A (y) fragments: rows jb*32+r32, chunk ks*2+hi at swizzled slot
            const v8h a0 = *(const v8h*)(buf + jb * 4096 + aoff0);
            const v8h a1 = *(const v8h*)(buf + jb * 4096 + aoff1);
            const v8h a2 = *(const v8h*)(buf + jb * 4096 + aoff2);
            const v8h a3 = *(const v8h*)(buf + jb * 4096 + aoff3);
            // C-init th[j] per C-row: rows (reg&3)+8*(reg>>2)+4*hi -> 4 broadcast b128
            const v4f tq0 = *(const v4f*)(tbuf + jb * 32 + hi * 4);
            const v4f tq1 = *(const v4f*)(tbuf + jb * 32 + hi * 4 + 8);
            const v4f tq2 = *(const v4f*)(tbuf + jb * 32 + hi * 4 + 16);
            const v4f tq3 = *(const v4f*)(tbuf + jb * 32 + hi * 4 + 24);
            v16f cin;
#pragma unroll
            for (int e = 0; e < 4; ++e) {
                cin[e]      = tq0[e];
                cin[e + 4]  = tq1[e];
                cin[e + 8]  = tq2[e];
                cin[e + 12] = tq3[e];
            }
#pragma unroll
            for (int g = 0; g < GROUPS; ++g) {
                v16f acc = __builtin_amdgcn_mfma_f32_32x32x16_f16(a0, b[g][0], cin, 0, 0, 0);
                acc = __builtin_amdgcn_mfma_f32_32x32x16_f16(a1, b[g][1], acc, 0, 0, 0);
                acc = __builtin_amdgcn_mfma_f32_32x32x16_f16(a2, b[g][2], acc, 0, 0, 0);
                acc = __builtin_amdgcn_mfma_f32_32x32x16_f16(a3, b[g][3], acc, 0, 0, 0);
                // j lives in the C-row dim -> pure register tree-max (no shuffles)
                const float m0 = fmaxf(fmaxf(acc[0],  acc[1]),  fmaxf(acc[2],  acc[3]));
                const float m1 = fmaxf(fmaxf(acc[4],  acc[5]),  fmaxf(acc[6],  acc[7]));
                const float m2 = fmaxf(fmaxf(acc[8],  acc[9]),  fmaxf(acc[10], acc[11]));
                const float m3 = fmaxf(fmaxf(acc[12], acc[13]), fmaxf(acc[14], acc[15]));
                maxs[g] = fmaxf(maxs[g], fmaxf(fmaxf(m0, m1), fmaxf(m2, m3)));
            }
        }
        __syncthreads();  // all waves done reading buf `cur`; prefetch drained
    }

    // epilogue: fold the two k-halves (rows +4*hi), store -2*max coalesced
#pragma unroll
    for (int g = 0; g < GROUPS; ++g) {
        float v = maxs[g];
        v = fmaxf(v, __shfl_xor(v, 32, 64));
        if (hi == 0)
            part[(size_t)jc * N_ROWS + i_wave + g * 32 + r32] = -2.f * v;
    }
}

// ---------- kernel 3: fused reduce ----------
// out += [ sum_i ( min_c part[c][i] + x2[i] ) ] / N + sum(psi) / M
__global__ __launch_bounds__(RBLOCK) void reduce_kernel(
    const float* __restrict__ part, const float* __restrict__ x2,
    const float* __restrict__ psi, float* __restrict__ out) {
    const int tid = threadIdx.x;
    const int gt  = blockIdx.x * RBLOCK + tid;    // [0, 32768)
    float m = part[gt];
#pragma unroll
    for (int c = 1; c < JC; ++c)
        m = fminf(m, part[(size_t)c * N_ROWS + gt]);
    float s = (m + x2[gt]) * (1.f / (float)N_ROWS);
    if (gt < M_COLS) s += psi[gt] * (1.f / (float)M_COLS);
    for (int off = 32; off > 0; off >>= 1) s += __shfl_down(s, off, 64);
    __shared__ float tmp[2];
    if ((tid & 63) == 0) tmp[tid >> 6] = s;
    __syncthreads();
    if (tid == 0) atomicAdd(out, tmp[0] + tmp[1]);
}

extern "C" void kernel_launch(void* const* d_in, const int* in_sizes, int n_in,
                              void* d_out, int out_size, void* d_ws, size_t ws_size,
                              hipStream_t stream) {
    const float* x   = (const float*)d_in[0];   // [N,D]
    const float* y   = (const float*)d_in[1];   // [M,D]
    const float* psi = (const float*)d_in[2];   // [M]
    float* out = (float*)d_out;

    // workspace layout
    float* part = (float*)d_ws;                            // JC*N floats = 1 MB
    float* th   = part + (size_t)JC * N_ROWS;              // M floats   = 32 KB
    float* x2   = th + (size_t)M_COLS;                     // N floats   = 128 KB
    _Float16* yh = (_Float16*)(x2 + (size_t)N_ROWS);       // M*D halves = 1 MB
    _Float16* xh = yh + (size_t)M_COLS * D_DIM;            // N*D halves = 4 MB

    prep_kernel<<<(M_COLS + N_ROWS) / 16, PBLOCK, 0, stream>>>(y, psi, x, yh, th, xh, x2, out);
    partial_min_kernel<<<dim3(N_ROWS / ROWS_PER_BLOCK, JC), BLOCK, 0, stream>>>(xh, yh, th, part);
    reduce_kernel<<<N_ROWS / RBLOCK, RBLOCK, 0, stream>>>(part, x2, psi, out);
}